// Round 7
// baseline (1418.226 us; speedup 1.0000x reference)
//
#include <hip/hip_runtime.h>
#include <cstdint>

// Problem constants
#define NB 32
#define IC 256
#define OC 256
#define H 56
#define WIDTH 56
#define OH 54
#define OW 54
#define HW (H*WIDTH)          // 3136
#define OHW (OH*OW)           // 2916
#define KTOT 2304             // 9 * 256, k = (kh*3+kw)*256 + c
#define M_TOT (NB*OHW)        // 93312
#define C8N (IC/8)            // 32 chunks of 8 channels

// GEMM tiling
#define BM 128                // spatial tile
#define BO 256                // out-channel tile (= all of OC: X staged once)
#define BK 32
#define KSTEPS (KTOT/BK)      // 72
#define MBLOCKS (M_TOT/BM)    // 729 = 3 * 243 -> exactly 3 blocks/CU, no tail
#define XBLK ((NB*C8N*HW)/256)  // 12544 xform blocks

// weights pre-tiled as per-K-step LDS images WITH chunk swizzle:
// g_qwt[step][r][cs][b] = sign(W[o=r][k = step*32 + (cs ^ ((r>>1)&3))*8 + b])
__device__ __align__(16) unsigned short g_qwt[KSTEPS*BO*BK];
// x as [n][c8][hw][8] bf16 (16B granule = 8 consecutive channels at one pixel)
__device__ __align__(16) unsigned short g_xq[NB*C8N*HW*8];

typedef __bf16 bf16x8 __attribute__((ext_vector_type(8)));
typedef float  f32x4  __attribute__((ext_vector_type(4)));

typedef __attribute__((address_space(1))) const unsigned int gas_u32;
typedef __attribute__((address_space(3))) unsigned int las_u32;
__device__ __forceinline__ void async_copy16(const void* g, void* l) {
  // global -> LDS direct copy, 16 B per lane; LDS dst = wave-uniform base + lane*16
  __builtin_amdgcn_global_load_lds((gas_u32*)g, (las_u32*)l, 16, 0, 0);
}

__device__ inline unsigned short f32_bf16(float f) {
  union { float f; unsigned int u; } v; v.f = f;
  unsigned int u = v.u;
  return (unsigned short)((u + 0x7FFFu + ((u >> 16) & 1u)) >> 16);  // RNE
}

// Counted vmcnt wait (T4): N outstanding VMEM ops may remain in flight.
#define WAITV(N) asm volatile("s_waitcnt vmcnt(" #N ")" ::: "memory")
// Raw barrier (no implicit vmcnt(0) drain, unlike __syncthreads()).
#define BARRIER() do { \
  __builtin_amdgcn_sched_barrier(0); \
  __builtin_amdgcn_s_barrier(); \
  __builtin_amdgcn_sched_barrier(0); \
} while (0)

// ---- Kernel 1: fused prep (x transform + weight repack), one launch ------
__global__ __launch_bounds__(256) void prep(const float* __restrict__ x,
                                            const float* __restrict__ w) {
  const int t = threadIdx.x;
  if (blockIdx.x < XBLK) {
    // x NCHW fp32 -> [n][c8][hw][8] bf16, LDS-free.
    int g = blockIdx.x * 256 + t;                   // granule id, < 3211264
    int hw = g % HW;
    int tc = g / HW;                                // n*32 + c8
    int c8 = tc & 31;
    int n  = tc >> 5;
    const float* src = x + (n*IC + c8*8)*HW + hw;
    unsigned int o[4];
    #pragma unroll
    for (int j = 0; j < 4; ++j) {
      unsigned int lo = f32_bf16(src[(2*j+0)*HW]);
      unsigned int hi = f32_bf16(src[(2*j+1)*HW]);
      o[j] = lo | (hi << 16);
    }
    *(uint4*)(&g_xq[g*8]) = *(uint4*)o;
  } else {
    // binarize + pre-tile weights (swizzled LDS image)
    int L = (blockIdx.x - XBLK) * 256 + t;          // < 589824
    int step = L >> 13;                             // /8192 (256 rows * 32 k)
    int r    = (L >> 5) & 255;
    int kc   = L & 31;
    int cs   = kc >> 3;                             // chunk slot 0..3
    int b    = kc & 7;
    int csrc = cs ^ ((r >> 1) & 3);                 // bank-conflict swizzle
    int k    = step*BK + csrc*8 + b;
    int pos  = k >> 8;                              // kh*3+kw
    int c    = k & 255;
    float v = w[r*2304 + c*9 + pos];
    g_qwt[L] = (v > 0.f) ? 0x3F80u : ((v < 0.f) ? 0xBF80u : 0u);
  }
}

// ---- Kernel 2: implicit-GEMM binary conv, 256o x 128m tile ---------------
// 8 waves (4o x 2m grid of 64x64 tiles), 16x16x32 MFMA (only conflict-free
// fragment pattern at BK=32 -- measured rounds 4/5).
// 2-deep LDS pipeline (48 KB -> 3 blocks/CU; 729 = 3*243 packs in ONE
// dispatch round, killing the 29% tail the 72 KB 3-deep version paid).
// Counted vmcnt: per step, COMPUTE(s); bar; STAGE(s+2 -> freed buf);
// WAITV(3) (= tile s+1 landed, s+2 stays in flight); bar.
__global__ __launch_bounds__(512, 6) void bconv_gemm(float* __restrict__ out) {
  __shared__ __align__(16) unsigned short Wl[2][BO*BK];   // 2 x 16 KB
  __shared__ __align__(16) unsigned short Xl[2][BM*BK];   // 2 x  8 KB  (48 KB)
  const int t = threadIdx.x;

  // XCD-aware bijective remap (729 = 8*91 + 1; xcd 0 gets 92 tiles).
  const int orig = blockIdx.x;
  const int xcd  = orig & 7;
  const int idx  = orig >> 3;
  const int bm   = (xcd == 0) ? idx : (92 + (xcd - 1)*91 + idx);
  const int m0   = bm * BM;

  // X staging: thread owns chunk q=t of 512. row i=q>>2, slot cs=q&3.
  // Source chunk pre-swizzled (cs ^ ((i>>1)&3)) -> linear LDS dest holds the
  // swizzled layout (linear dest + pre-swizzled source + swizzled read).
  int xbase;
  {
    const int i   = t >> 2;                         // m-row 0..127
    const int cs  = t & 3;
    const int csw = cs ^ ((i >> 1) & 3);
    int m  = m0 + i;
    int n  = m / OHW;
    int rm = m - n*OHW;
    int oh = rm / OW;
    int ow = rm - oh*OW;
    xbase = ((n*C8N + csw)*HW + oh*WIDTH + ow) * 8;
  }

  const int lane = t & 63;
  const int wv   = t >> 6;                          // 0..7
  const int col  = lane & 15;
  const int quad = lane >> 4;
  const int wo   = (wv >> 1) * 64;                  // wave o-offset (0,64,128,192)
  const int wm   = (wv & 1) * 64;                   // wave m-offset (0,64)
  // read-side swizzle: rows are (multiple of 16)+col -> ((row>>1)&3)==((col>>1)&3)
  const int sw   = (quad ^ ((col >> 1) & 3)) * 8;
  int aoff[4], boff[4];
  #pragma unroll
  for (int i = 0; i < 4; ++i) {
    aoff[i] = (wo + i*16 + col)*BK + sw;
    boff[i] = (wm + i*16 + col)*BK + sw;
  }

  auto STAGE = [&](int step, int buf) {
    const unsigned short* ws = g_qwt + step*(BO*BK);
    async_copy16(&ws[t*8],       &Wl[buf][t*8]);         // W: 1024 chunks, linear
    async_copy16(&ws[(t+512)*8], &Wl[buf][(t+512)*8]);
    const int pos = step >> 3;                            // 8 steps per position
    const int kh  = pos / 3;
    const int kw  = pos - kh*3;
    const int xo  = xbase + (((step & 7)*4)*HW + kh*WIDTH + kw)*8;
    async_copy16(&g_xq[xo], &Xl[buf][t*8]);               // X: im2col gather
  };

  f32x4 acc[4][4];
  #pragma unroll
  for (int a = 0; a < 4; ++a)
    #pragma unroll
    for (int b = 0; b < 4; ++b)
      acc[a][b] = (f32x4){0.f, 0.f, 0.f, 0.f};

  auto COMPUTE = [&](const unsigned short* Wb, const unsigned short* Xb) {
    bf16x8 av[4], bv[4];
    #pragma unroll
    for (int i = 0; i < 4; ++i) av[i] = *(const bf16x8*)(&Wb[aoff[i]]);
    #pragma unroll
    for (int i = 0; i < 4; ++i) bv[i] = *(const bf16x8*)(&Xb[boff[i]]);
    __builtin_amdgcn_s_setprio(1);
    #pragma unroll
    for (int io = 0; io < 4; ++io)
      #pragma unroll
      for (int im = 0; im < 4; ++im)
        acc[io][im] = __builtin_amdgcn_mfma_f32_16x16x32_bf16(av[io], bv[im], acc[io][im], 0, 0, 0);
    __builtin_amdgcn_s_setprio(0);
  };

  // Prologue: stages 0,1 in flight (3 copies each per thread).
  STAGE(0, 0);
  STAGE(1, 1);
  WAITV(3);            // tile 0 landed (tile 1's 3 copies remain in flight)
  BARRIER();

  // Main loop: tiles 0..69 (35 iters x2); stages tiles 2..71.
  // Ledger at loop top: 3 in flight (tile s+1).
  #pragma unroll 1
  for (int s = 0; s < 70; s += 2) {
    COMPUTE(Wl[0], Xl[0]);                // tile s   (tile s+1 in flight)
    BARRIER();                            // all waves done reading buf 0
    STAGE(s + 2, 0);                      // 6 in flight
    WAITV(3);                             // tile s+1 landed (s+2 remains)
    BARRIER();

    COMPUTE(Wl[1], Xl[1]);                // tile s+1 (tile s+2 in flight)
    BARRIER();                            // all waves done reading buf 1
    STAGE(s + 3, 1);                      // 6 in flight
    WAITV(3);                             // tile s+2 landed (s+3 remains)
    BARRIER();
  }

  // Tail: tiles 70 (buf0) and 71 (buf1).
  COMPUTE(Wl[0], Xl[0]);                  // tile 70
  WAITV(0);                               // tile 71 landed
  BARRIER();
  COMPUTE(Wl[1], Xl[1]);                  // tile 71

  // Epilogue: D col=(lane&15)->m, row=(quad*4+r)->o. out[n][o][oh][ow].
  #pragma unroll
  for (int im = 0; im < 4; ++im) {
    int m  = m0 + wm + im*16 + col;
    int n  = m / OHW;
    int rm = m - n*OHW;
    float* obase = out + n*(OC*OHW) + rm;
    #pragma unroll
    for (int io = 0; io < 4; ++io) {
      int orow = wo + io*16 + quad*4;
      #pragma unroll
      for (int r = 0; r < 4; ++r)
        obase[(orow + r)*OHW] = acc[io][im][r];
    }
  }
}

extern "C" void kernel_launch(void* const* d_in, const int* in_sizes, int n_in,
                              void* d_out, int out_size, void* d_ws, size_t ws_size,
                              hipStream_t stream) {
  const float* x = (const float*)d_in[0];   // [32,256,56,56] fp32
  const float* w = (const float*)d_in[1];   // [256,256,3,3] fp32
  float* out = (float*)d_out;               // [32,256,54,54] fp32

  prep<<<dim3(XBLK + (KSTEPS*BO*BK)/256), 256, 0, stream>>>(x, w);  // 14848 blocks
  bconv_gemm<<<dim3(MBLOCKS), 512, 0, stream>>>(out);               // 729 blocks
}

// Round 9
// 304.972 us; speedup vs baseline: 4.6503x; 4.6503x over previous
//
#include <hip/hip_runtime.h>
#include <cstdint>

// Problem constants
#define NB 32
#define IC 256
#define OC 256
#define H 56
#define WIDTH 56
#define OH 54
#define OW 54
#define HW (H*WIDTH)          // 3136
#define OHW (OH*OW)           // 2916
#define KTOT 2304             // 9 * 256, k = (kh*3+kw)*256 + c
#define M_TOT (NB*OHW)        // 93312
#define C8N (IC/8)            // 32 chunks of 8 channels

// GEMM tiling
#define BM 96                 // spatial tile: 93312/96 = 972 blocks = 512+460
                              // -> 95% slot packing at 2 blocks/CU (vs 71% @BM=128)
#define BO 256                // out-channel tile (= all of OC: X staged once)
#define BK 32
#define KSTEPS (KTOT/BK)      // 72
#define MBLOCKS (M_TOT/BM)    // 972
#define XBLK ((NB*C8N*HW)/256)  // 12544 xform blocks

// weights pre-tiled as per-K-step LDS images WITH chunk swizzle:
// g_qwt[step][r][cs][b] = sign(W[o=r][k = step*32 + (cs ^ ((r>>1)&3))*8 + b])
__device__ __align__(16) unsigned short g_qwt[KSTEPS*BO*BK];
// x as [n][c8][hw][8] bf16 (16B granule = 8 consecutive channels at one pixel)
__device__ __align__(16) unsigned short g_xq[NB*C8N*HW*8];

typedef __bf16 bf16x8 __attribute__((ext_vector_type(8)));
typedef float  f32x4  __attribute__((ext_vector_type(4)));

typedef __attribute__((address_space(1))) const unsigned int gas_u32;
typedef __attribute__((address_space(3))) unsigned int las_u32;
__device__ __forceinline__ void async_copy16(const void* g, void* l) {
  // global -> LDS direct copy, 16 B per lane; LDS dst = wave-uniform base + lane*16
  __builtin_amdgcn_global_load_lds((gas_u32*)g, (las_u32*)l, 16, 0, 0);
}

__device__ inline unsigned short f32_bf16(float f) {
  union { float f; unsigned int u; } v; v.f = f;
  unsigned int u = v.u;
  return (unsigned short)((u + 0x7FFFu + ((u >> 16) & 1u)) >> 16);  // RNE
}

// Counted vmcnt wait (T4): N outstanding VMEM ops may remain in flight.
#define WAITV(N) asm volatile("s_waitcnt vmcnt(" #N ")" ::: "memory")
// Raw barrier (no implicit vmcnt(0) drain, unlike __syncthreads()).
#define BARRIER() do { \
  __builtin_amdgcn_sched_barrier(0); \
  __builtin_amdgcn_s_barrier(); \
  __builtin_amdgcn_sched_barrier(0); \
} while (0)

// ---- Kernel 1: fused prep (x transform + weight repack), one launch ------
__global__ __launch_bounds__(256) void prep(const float* __restrict__ x,
                                            const float* __restrict__ w) {
  const int t = threadIdx.x;
  if (blockIdx.x < XBLK) {
    // x NCHW fp32 -> [n][c8][hw][8] bf16, LDS-free.
    int g = blockIdx.x * 256 + t;                   // granule id, < 3211264
    int hw = g % HW;
    int tc = g / HW;                                // n*32 + c8
    int c8 = tc & 31;
    int n  = tc >> 5;
    const float* src = x + (n*IC + c8*8)*HW + hw;
    unsigned int o[4];
    #pragma unroll
    for (int j = 0; j < 4; ++j) {
      unsigned int lo = f32_bf16(src[(2*j+0)*HW]);
      unsigned int hi = f32_bf16(src[(2*j+1)*HW]);
      o[j] = lo | (hi << 16);
    }
    *(uint4*)(&g_xq[g*8]) = *(uint4*)o;
  } else {
    // binarize + pre-tile weights (swizzled LDS image)
    int L = (blockIdx.x - XBLK) * 256 + t;          // < 589824
    int step = L >> 13;                             // /8192 (256 rows * 32 k)
    int r    = (L >> 5) & 255;
    int kc   = L & 31;
    int cs   = kc >> 3;                             // chunk slot 0..3
    int b    = kc & 7;
    int csrc = cs ^ ((r >> 1) & 3);                 // bank-conflict swizzle
    int k    = step*BK + csrc*8 + b;
    int pos  = k >> 8;                              // kh*3+kw
    int c    = k & 255;
    float v = w[r*2304 + c*9 + pos];
    g_qwt[L] = (v > 0.f) ? 0x3F80u : ((v < 0.f) ? 0xBF80u : 0u);
  }
}

// ---- Kernel 2: implicit-GEMM binary conv, 256o x 96m tile ----------------
// 8 waves (4o x 2m grid of 64x48 tiles), 16x16x32 MFMA (only conflict-free
// fragment pattern at BK=32 -- measured rounds 4/5).
// 2-deep LDS pipeline, counted vmcnt exactly as round 5's schedule.
// REGISTER WALL (round-7 lesson): per-SIMD pool = 512 regs/lane; 8-wave
// blocks with 48-acc threads fit 4 waves/SIMD (2 blocks/CU) -- never force
// more via launch_bounds (it spills acc to scratch: 5.5 GB HBM, 9x slower).
// LDS padded to 54 KB to PIN 2 blocks/CU (3 would drop packing to 63%).
// Staging ledger: every thread issues exactly 3 copies/step (2 W + 1 X for
// waves 0-5; waves 6-7 re-copy their own W chunk as a dummy) so WAITV(3)
// means "previous tile fully landed" uniformly.
__global__ __launch_bounds__(512) void bconv_gemm(float* __restrict__ out) {
  __shared__ __align__(16) unsigned short Wl[2][BO*BK + 2560]; // 2 x 21 KB (5KB pad)
  __shared__ __align__(16) unsigned short Xl[2][BM*BK];        // 2 x  6 KB -> 54 KB total
  const int t = threadIdx.x;

  // XCD-aware bijective remap: 972 = 8*121 + 4 (m204 formula, q=121, r=4).
  const int orig = blockIdx.x;
  const int xcd  = orig & 7;
  const int idx  = orig >> 3;
  const int base = (xcd < 4) ? xcd*122 : (4*122 + (xcd - 4)*121);
  const int bm   = base + idx;
  const int m0   = bm * BM;

  // X staging: 384 chunks (96 rows x 4 slots); thread t<384 owns chunk q=t.
  // row i=q>>2, slot cs=q&3, source pre-swizzled (cs ^ ((i>>1)&3)) -> linear
  // LDS dest holds the swizzled layout.
  int xbase;
  {
    const int i   = (t >> 2) % 96;                  // m-row 0..95
    const int cs  = t & 3;
    const int csw = cs ^ ((i >> 1) & 3);
    int m  = m0 + i;
    int n  = m / OHW;
    int rm = m - n*OHW;
    int oh = rm / OW;
    int ow = rm - oh*OW;
    xbase = ((n*C8N + csw)*HW + oh*WIDTH + ow) * 8;
  }

  const int lane = t & 63;
  const int wv   = t >> 6;                          // 0..7
  const int col  = lane & 15;
  const int quad = lane >> 4;
  const int wo   = (wv >> 1) * 64;                  // wave o-offset (0,64,128,192)
  const int wm   = (wv & 1) * 48;                   // wave m-offset (0,48)
  // read-side swizzle: rows are (multiple of 16)+col -> ((row>>1)&3)==((col>>1)&3)
  const int sw   = (quad ^ ((col >> 1) & 3)) * 8;
  int aoff[4], boff[3];
  #pragma unroll
  for (int i = 0; i < 4; ++i)
    aoff[i] = (wo + i*16 + col)*BK + sw;
  #pragma unroll
  for (int i = 0; i < 3; ++i)
    boff[i] = (wm + i*16 + col)*BK + sw;

  auto STAGE = [&](int step, int buf) {
    const unsigned short* ws = g_qwt + step*(BO*BK);
    async_copy16(&ws[t*8],       &Wl[buf][t*8]);         // W: 1024 chunks, linear
    async_copy16(&ws[(t+512)*8], &Wl[buf][(t+512)*8]);
    if (t < 384) {                                        // wave-uniform (wv<6)
      const int pos = step >> 3;                          // 8 steps per position
      const int kh  = pos / 3;
      const int kw  = pos - kh*3;
      const int xo  = xbase + (((step & 7)*4)*HW + kh*WIDTH + kw)*8;
      async_copy16(&g_xq[xo], &Xl[buf][t*8]);             // X: im2col gather
    } else {
      async_copy16(&ws[t*8], &Wl[buf][t*8]);              // dummy: uniform vmcnt
    }
  };

  f32x4 acc[4][3];
  #pragma unroll
  for (int a = 0; a < 4; ++a)
    #pragma unroll
    for (int b = 0; b < 3; ++b)
      acc[a][b] = (f32x4){0.f, 0.f, 0.f, 0.f};

  auto COMPUTE = [&](const unsigned short* Wb, const unsigned short* Xb) {
    bf16x8 av[4], bv[3];
    #pragma unroll
    for (int i = 0; i < 4; ++i) av[i] = *(const bf16x8*)(&Wb[aoff[i]]);
    #pragma unroll
    for (int i = 0; i < 3; ++i) bv[i] = *(const bf16x8*)(&Xb[boff[i]]);
    __builtin_amdgcn_s_setprio(1);
    #pragma unroll
    for (int io = 0; io < 4; ++io)
      #pragma unroll
      for (int im = 0; im < 3; ++im)
        acc[io][im] = __builtin_amdgcn_mfma_f32_16x16x32_bf16(av[io], bv[im], acc[io][im], 0, 0, 0);
    __builtin_amdgcn_s_setprio(0);
  };

  // Prologue: stages 0,1 in flight (3 copies each per thread).
  STAGE(0, 0);
  STAGE(1, 1);
  WAITV(3);            // tile 0 landed (tile 1's 3 copies remain in flight)
  BARRIER();

  // Main loop: tiles 0..69 (35 iters x2); stages tiles 2..71.
  #pragma unroll 1
  for (int s = 0; s < 70; s += 2) {
    COMPUTE(Wl[0], Xl[0]);                // tile s   (tile s+1 in flight)
    BARRIER();                            // all waves done reading buf 0
    STAGE(s + 2, 0);                      // 6 in flight
    WAITV(3);                             // tile s+1 landed (s+2 remains)
    BARRIER();

    COMPUTE(Wl[1], Xl[1]);                // tile s+1 (tile s+2 in flight)
    BARRIER();                            // all waves done reading buf 1
    STAGE(s + 3, 1);                      // 6 in flight
    WAITV(3);                             // tile s+2 landed (s+3 remains)
    BARRIER();
  }

  // Tail: tiles 70 (buf0) and 71 (buf1).
  COMPUTE(Wl[0], Xl[0]);                  // tile 70
  WAITV(0);                               // tile 71 landed
  BARRIER();
  COMPUTE(Wl[1], Xl[1]);                  // tile 71

  // Epilogue: D col=(lane&15)->m, row=(quad*4+r)->o. out[n][o][oh][ow].
  #pragma unroll
  for (int im = 0; im < 3; ++im) {
    int m  = m0 + wm + im*16 + col;
    int n  = m / OHW;
    int rm = m - n*OHW;
    float* obase = out + n*(OC*OHW) + rm;
    #pragma unroll
    for (int io = 0; io < 4; ++io) {
      int orow = wo + io*16 + quad*4;
      #pragma unroll
      for (int r = 0; r < 4; ++r)
        obase[(orow + r)*OHW] = acc[io][im][r];
    }
  }
}

extern "C" void kernel_launch(void* const* d_in, const int* in_sizes, int n_in,
                              void* d_out, int out_size, void* d_ws, size_t ws_size,
                              hipStream_t stream) {
  const float* x = (const float*)d_in[0];   // [32,256,56,56] fp32
  const float* w = (const float*)d_in[1];   // [256,256,3,3] fp32
  float* out = (float*)d_out;               // [32,256,54,54] fp32

  prep<<<dim3(XBLK + (KSTEPS*BO*BK)/256), 256, 0, stream>>>(x, w);  // 14848 blocks
  bconv_gemm<<<dim3(MBLOCKS), 512, 0, stream>>>(out);               // 972 blocks
}

// Round 10
// 303.198 us; speedup vs baseline: 4.6776x; 1.0059x over previous
//
#include <hip/hip_runtime.h>
#include <cstdint>

// Problem constants
#define NB 32
#define IC 256
#define OC 256
#define H 56
#define WIDTH 56
#define OH 54
#define OW 54
#define HW (H*WIDTH)          // 3136
#define OHW (OH*OW)           // 2916
#define KTOT 2304             // 9 * 256, k = (kh*3+kw)*256 + c
#define M_TOT (NB*OHW)        // 93312
#define C8N (IC/8)            // 32 chunks of 8 channels

// GEMM tiling
#define BM 96                 // spatial tile: 93312/96 = 972 blocks = 512+460
                              // -> 95% slot packing at 2 blocks/CU (vs 71% @BM=128)
#define BO 256                // out-channel tile (= all of OC: X staged once)
#define BK 32
#define KSTEPS (KTOT/BK)      // 72
#define MBLOCKS (M_TOT/BM)    // 972
#define XBLK ((NB*C8N*HW)/256)  // 12544 xform blocks

// weights pre-tiled as per-K-step LDS images WITH chunk swizzle:
// g_qwt[step][r][cs][b] = sign(W[o=r][k = step*32 + (cs ^ ((r>>1)&3))*8 + b])
__device__ __align__(16) unsigned short g_qwt[KSTEPS*BO*BK];
// x as [n][c8][hw][8] bf16 (16B granule = 8 consecutive channels at one pixel)
__device__ __align__(16) unsigned short g_xq[NB*C8N*HW*8];

typedef __bf16 bf16x8 __attribute__((ext_vector_type(8)));
typedef float  f32x4  __attribute__((ext_vector_type(4)));

typedef __attribute__((address_space(1))) const unsigned int gas_u32;
typedef __attribute__((address_space(3))) unsigned int las_u32;
__device__ __forceinline__ void async_copy16(const void* g, void* l) {
  // global -> LDS direct copy, 16 B per lane; LDS dst = wave-uniform base + lane*16
  __builtin_amdgcn_global_load_lds((gas_u32*)g, (las_u32*)l, 16, 0, 0);
}

__device__ inline unsigned short f32_bf16(float f) {
  union { float f; unsigned int u; } v; v.f = f;
  unsigned int u = v.u;
  return (unsigned short)((u + 0x7FFFu + ((u >> 16) & 1u)) >> 16);  // RNE
}

// Counted vmcnt wait (T4): N outstanding VMEM ops may remain in flight.
#define WAITV(N) asm volatile("s_waitcnt vmcnt(" #N ")" ::: "memory")
// Raw barrier (no implicit vmcnt(0) drain, unlike __syncthreads()).
#define BARRIER() do { \
  __builtin_amdgcn_sched_barrier(0); \
  __builtin_amdgcn_s_barrier(); \
  __builtin_amdgcn_sched_barrier(0); \
} while (0)

// ---- Kernel 1: fused prep (x transform + weight repack), one launch ------
__global__ __launch_bounds__(256) void prep(const float* __restrict__ x,
                                            const float* __restrict__ w) {
  const int t = threadIdx.x;
  if (blockIdx.x < XBLK) {
    // x NCHW fp32 -> [n][c8][hw][8] bf16, LDS-free.
    int g = blockIdx.x * 256 + t;                   // granule id, < 3211264
    int hw = g % HW;
    int tc = g / HW;                                // n*32 + c8
    int c8 = tc & 31;
    int n  = tc >> 5;
    const float* src = x + (n*IC + c8*8)*HW + hw;
    unsigned int o[4];
    #pragma unroll
    for (int j = 0; j < 4; ++j) {
      unsigned int lo = f32_bf16(src[(2*j+0)*HW]);
      unsigned int hi = f32_bf16(src[(2*j+1)*HW]);
      o[j] = lo | (hi << 16);
    }
    *(uint4*)(&g_xq[g*8]) = *(uint4*)o;
  } else {
    // binarize + pre-tile weights (swizzled LDS image)
    int L = (blockIdx.x - XBLK) * 256 + t;          // < 589824
    int step = L >> 13;                             // /8192 (256 rows * 32 k)
    int r    = (L >> 5) & 255;
    int kc   = L & 31;
    int cs   = kc >> 3;                             // chunk slot 0..3
    int b    = kc & 7;
    int csrc = cs ^ ((r >> 1) & 3);                 // bank-conflict swizzle
    int k    = step*BK + csrc*8 + b;
    int pos  = k >> 8;                              // kh*3+kw
    int c    = k & 255;
    float v = w[r*2304 + c*9 + pos];
    g_qwt[L] = (v > 0.f) ? 0x3F80u : ((v < 0.f) ? 0xBF80u : 0u);
  }
}

// ---- Kernel 2: implicit-GEMM binary conv, 256o x 96m tile ----------------
// 8 waves (4o x 2m grid of 64x48 tiles), 16x16x32 MFMA (only conflict-free
// fragment pattern at BK=32 -- measured rounds 4/5).
// 3-deep LDS ring (66 KB -> naturally exactly 2 blocks/CU: 132 < 160 < 198),
// TWO-phase prefetch cover: per phase, COMPUTE(s); BAR; STAGE(s+3 -> freed
// buf); WAITV(6) (= tile s+1 landed, and s+1 was ISSUED two phases ago ->
// ~2 compute phases of latency cover for HBM-resident X gathers); BAR.
// REGISTER WALL (round-7 lesson): per-SIMD pool = 512 regs/lane; never force
// >2 blocks/CU via launch_bounds (acc spills to scratch, 9x slower).
// Staging ledger: every thread issues exactly 3 copies/step (2 W + 1 X for
// waves 0-5; waves 6-7 re-copy their own W chunk as a dummy) so the counted
// vmcnt is uniform across all waves.
__global__ __launch_bounds__(512) void bconv_gemm(float* __restrict__ out) {
  __shared__ __align__(16) unsigned short Wl[3][BO*BK];   // 3 x 16 KB
  __shared__ __align__(16) unsigned short Xl[3][BM*BK];   // 3 x  6 KB -> 66 KB
  const int t = threadIdx.x;

  // XCD-aware bijective remap: 972 = 8*121 + 4 (m204 formula, q=121, r=4).
  const int orig = blockIdx.x;
  const int xcd  = orig & 7;
  const int idx  = orig >> 3;
  const int base = (xcd < 4) ? xcd*122 : (4*122 + (xcd - 4)*121);
  const int bm   = base + idx;
  const int m0   = bm * BM;

  // X staging: 384 chunks (96 rows x 4 slots); thread t<384 owns chunk q=t.
  // row i=q>>2, slot cs=q&3, source pre-swizzled (cs ^ ((i>>1)&3)) -> linear
  // LDS dest holds the swizzled layout.
  int xbase;
  {
    const int i   = (t >> 2) % 96;                  // m-row 0..95
    const int cs  = t & 3;
    const int csw = cs ^ ((i >> 1) & 3);
    int m  = m0 + i;
    int n  = m / OHW;
    int rm = m - n*OHW;
    int oh = rm / OW;
    int ow = rm - oh*OW;
    xbase = ((n*C8N + csw)*HW + oh*WIDTH + ow) * 8;
  }

  const int lane = t & 63;
  const int wv   = t >> 6;                          // 0..7
  const int col  = lane & 15;
  const int quad = lane >> 4;
  const int wo   = (wv >> 1) * 64;                  // wave o-offset (0,64,128,192)
  const int wm   = (wv & 1) * 48;                   // wave m-offset (0,48)
  // read-side swizzle: rows are (multiple of 16)+col -> ((row>>1)&3)==((col>>1)&3)
  const int sw   = (quad ^ ((col >> 1) & 3)) * 8;
  int aoff[4], boff[3];
  #pragma unroll
  for (int i = 0; i < 4; ++i)
    aoff[i] = (wo + i*16 + col)*BK + sw;
  #pragma unroll
  for (int i = 0; i < 3; ++i)
    boff[i] = (wm + i*16 + col)*BK + sw;

  auto STAGE = [&](int step, int buf) {
    const unsigned short* ws = g_qwt + step*(BO*BK);
    async_copy16(&ws[t*8],       &Wl[buf][t*8]);         // W: 1024 chunks, linear
    async_copy16(&ws[(t+512)*8], &Wl[buf][(t+512)*8]);
    if (t < 384) {                                        // wave-uniform (wv<6)
      const int pos = step >> 3;                          // 8 steps per position
      const int kh  = pos / 3;
      const int kw  = pos - kh*3;
      const int xo  = xbase + (((step & 7)*4)*HW + kh*WIDTH + kw)*8;
      async_copy16(&g_xq[xo], &Xl[buf][t*8]);             // X: im2col gather
    } else {
      async_copy16(&ws[t*8], &Wl[buf][t*8]);              // dummy: uniform vmcnt
    }
  };

  f32x4 acc[4][3];
  #pragma unroll
  for (int a = 0; a < 4; ++a)
    #pragma unroll
    for (int b = 0; b < 3; ++b)
      acc[a][b] = (f32x4){0.f, 0.f, 0.f, 0.f};

  auto COMPUTE = [&](const unsigned short* Wb, const unsigned short* Xb) {
    bf16x8 av[4], bv[3];
    #pragma unroll
    for (int i = 0; i < 4; ++i) av[i] = *(const bf16x8*)(&Wb[aoff[i]]);
    #pragma unroll
    for (int i = 0; i < 3; ++i) bv[i] = *(const bf16x8*)(&Xb[boff[i]]);
    __builtin_amdgcn_s_setprio(1);
    #pragma unroll
    for (int io = 0; io < 4; ++io)
      #pragma unroll
      for (int im = 0; im < 3; ++im)
        acc[io][im] = __builtin_amdgcn_mfma_f32_16x16x32_bf16(av[io], bv[im], acc[io][im], 0, 0, 0);
    __builtin_amdgcn_s_setprio(0);
  };

  // Prologue: fill the 3-deep ring (9 copies in flight per thread).
  STAGE(0, 0);
  STAGE(1, 1);
  STAGE(2, 2);
  WAITV(6);            // tile 0 landed; {1,2} in flight
  BARRIER();

  // Main loop: phases for tiles 0..68 (23 iters x3), staging tiles 3..71.
  // Phase invariant at entry: {s+1, s+2} in flight (6 loads).
  #pragma unroll 1
  for (int s = 0; s < 69; s += 3) {
    COMPUTE(Wl[0], Xl[0]);                // tile s
    BARRIER();                            // all waves done reading buf 0
    STAGE(s + 3, 0);                      // 9 in flight
    WAITV(6);                             // tile s+1 landed (issued 2 phases ago)
    BARRIER();

    COMPUTE(Wl[1], Xl[1]);                // tile s+1
    BARRIER();
    STAGE(s + 4, 1);
    WAITV(6);                             // tile s+2 landed
    BARRIER();

    COMPUTE(Wl[2], Xl[2]);                // tile s+2
    BARRIER();
    STAGE(s + 5, 2);
    WAITV(6);                             // tile s+3 landed
    BARRIER();
  }

  // Tail: tiles 69 (b0), 70 (b1), 71 (b2); in-flight {70,71} at entry.
  COMPUTE(Wl[0], Xl[0]);                  // tile 69
  WAITV(3);                               // tile 70 landed
  BARRIER();
  COMPUTE(Wl[1], Xl[1]);                  // tile 70
  WAITV(0);                               // tile 71 landed
  BARRIER();
  COMPUTE(Wl[2], Xl[2]);                  // tile 71

  // Epilogue: D col=(lane&15)->m, row=(quad*4+r)->o. out[n][o][oh][ow].
  #pragma unroll
  for (int im = 0; im < 3; ++im) {
    int m  = m0 + wm + im*16 + col;
    int n  = m / OHW;
    int rm = m - n*OHW;
    float* obase = out + n*(OC*OHW) + rm;
    #pragma unroll
    for (int io = 0; io < 4; ++io) {
      int orow = wo + io*16 + quad*4;
      #pragma unroll
      for (int r = 0; r < 4; ++r)
        obase[(orow + r)*OHW] = acc[io][im][r];
    }
  }
}

extern "C" void kernel_launch(void* const* d_in, const int* in_sizes, int n_in,
                              void* d_out, int out_size, void* d_ws, size_t ws_size,
                              hipStream_t stream) {
  const float* x = (const float*)d_in[0];   // [32,256,56,56] fp32
  const float* w = (const float*)d_in[1];   // [256,256,3,3] fp32
  float* out = (float*)d_out;               // [32,256,54,54] fp32

  prep<<<dim3(XBLK + (KSTEPS*BO*BK)/256), 256, 0, stream>>>(x, w);  // 14848 blocks
  bconv_gemm<<<dim3(MBLOCKS), 512, 0, stream>>>(out);               // 972 blocks
}